// Round 2
// baseline (3461.201 us; speedup 1.0000x reference)
//
#include <hip/hip_runtime.h>
#include <math.h>

// Problem constants: B=32, T=64, N=128, D=64, E=5.  Time chunked: TC=16, 4 chunks.
// Workspace layout (float element offsets; flags occupy first 4 KB as uint32)
constexpr size_t WS_VV  = 1024;                  // 128*5
constexpr size_t WS_TOT = 2048;                  // 32*128
constexpr size_t WS_RS  = 8192;                  // 262144
constexpr size_t WS_WH  = 270336;                // 3*128*64*64 = 1572864
constexpr size_t WS_WX  = 1843200;               // 3*128*65*64 = 1597440
constexpr size_t WS_BF  = 3440640;               // 3*128*64 = 24576
constexpr size_t WS_H   = 3465216;               // 262144
constexpr size_t WS_CH  = 3727360;               // 262144
constexpr size_t WS_CX  = 3989504;               // 128*512*65 = 4259840   [n][b*16+tl][65]
constexpr size_t WS_GXR = 8249344;               // 128*16*32*64 = 4194304 [n][tl][b][o]
constexpr size_t WS_GXU = 12443648;
constexpr size_t WS_CXC = 16637952;
// end = 20832256 floats = 79.5 MiB

__device__ __forceinline__ float sigm(float x){ return 1.f/(1.f+expf(-x)); }

// ---------------- vv = relu(vpe@W1+b1)@W2+b2 ----------------
__global__ void k_vv(const float* __restrict__ vpe, const float* __restrict__ W1,
                     const float* __restrict__ b1, const float* __restrict__ W2,
                     const float* __restrict__ b2, float* __restrict__ ws){
  int n = blockIdx.x, tid = threadIdx.x;
  __shared__ float hid[128];
  if (tid < 128){
    float acc = b1[tid];
    for (int k=0;k<768;k++) acc = fmaf(vpe[n*768+k], W1[k*128+tid], acc);
    hid[tid] = fmaxf(acc, 0.f);
  }
  __syncthreads();
  if (tid < 5){
    float acc = b2[tid];
    for (int h=0;h<128;h++) acc = fmaf(hid[h], W2[h*5+tid], acc);
    ws[WS_VV + n*5 + tid] = acc;
  }
}

// ---------------- fold per-node weights: Wn = sum_e vv[n,e]*W[e] ----------------
__global__ void k_fold(const float* __restrict__ Wr, const float* __restrict__ Wu,
                       const float* __restrict__ Wc, const float* __restrict__ br,
                       const float* __restrict__ bu, const float* __restrict__ bc,
                       float* __restrict__ ws){
  int bid = blockIdx.x; int g = bid>>7; int n = bid&127;
  const float* W  = (g==0)?Wr:(g==1)?Wu:Wc;
  const float* bb = (g==0)?br:(g==1)?bu:bc;
  float v[5];
#pragma unroll
  for (int e=0;e<5;e++) v[e] = ws[WS_VV + n*5 + e];
  for (int idx=threadIdx.x; idx<129*64; idx+=256){
    int i = idx>>6, o = idx&63;
    float a = 0.f;
#pragma unroll
    for (int e=0;e<5;e++) a = fmaf(v[e], W[(e*129+i)*64+o], a);
    if (i < 65) ws[WS_WX + (size_t)(g*128+n)*4160 + i*64 + o] = a;
    else        ws[WS_WH + (size_t)(g*128+n)*4096 + (i-65)*64 + o] = a;
  }
  if (threadIdx.x < 64){
    int o = threadIdx.x; float a = 0.f;
#pragma unroll
    for (int e=0;e<5;e++) a = fmaf(v[e], bb[e*64+o], a);
    ws[WS_BF + (g*128+n)*64 + o] = a;
  }
}

// ---------------- tot[b,n] = sum_t mask ----------------
__global__ void k_tot(const float* __restrict__ mask, float* __restrict__ ws){
  int id = blockIdx.x*256 + threadIdx.x;     // 4096
  int b = id>>7, n = id&127;
  float s = 0.f;
  for (int t=0;t<64;t++) s += mask[(b*64+t)*128 + n];
  ws[WS_TOT + b*128 + n] = s;
}

// ---------------- rs = 0.5*tanh(avg/(tot+1)) ----------------
__global__ void k_rs(const float* __restrict__ avg, float* __restrict__ ws){
  int id = blockIdx.x*256 + threadIdx.x;     // 262144
  int b = id>>13, n = id&127;
  float tot = ws[WS_TOT + b*128 + n];
  ws[WS_RS + id] = 0.5f * tanhf(avg[id] / (tot + 1.f));
}

// ---------------- P4a (per chunk): combX[b,t,i,:] = adj(b,t) @ xtilde(b,t), stored [i][b*16+tl][65] ----------------
__global__ __launch_bounds__(256) void p4a(const float* __restrict__ obs,
      const float* __restrict__ mask, const float* __restrict__ adjI,
      const float* __restrict__ rW, const int* __restrict__ lengths,
      float* __restrict__ ws, int c0){
  int rc = blockIdx.x;                 // b*16 + tl
  int b = rc>>4, tl = rc&15, t = c0 + tl;
  if (t >= lengths[b]) return;
  int rt = b*64 + t;
  __shared__ float xt[64*68];          // x-tile for current j-half, col 64 = rs
  __shared__ float adjh[128*68];       // adj[i][j-half]
  __shared__ float rs_l[128], m_l[128];
  int tid = threadIdx.x;
  if (tid < 128){ rs_l[tid] = ws[WS_RS + rt*128 + tid]; m_l[tid] = mask[rt*128 + tid]; }
  __syncthreads();
  int it = tid>>3, ft = tid&7, i0 = it*4, f0 = ft*8;
  float4 aL[4], aH[4]; float a64[4];
#pragma unroll
  for (int ii=0;ii<4;ii++){ aL[ii]=make_float4(0,0,0,0); aH[ii]=make_float4(0,0,0,0); a64[ii]=0.f; }
  for (int half=0; half<2; half++){
    __syncthreads();
    int j0 = half*64;
    for (int idx=tid; idx<4096; idx+=256){
      int jl = idx>>6, f = idx&63;
      xt[jl*68+f] = obs[(size_t)rt*8192 + (j0+jl)*64 + f];
    }
    if (tid < 64) xt[tid*68+64] = rs_l[j0+tid];
    for (int idx=tid; idx<8192; idx+=256){
      int i = idx>>6, jl = idx&63, j = j0+jl;
      float a;
      if (i == j) a = 1.f;
      else {
        int gi = i*128 + j;
        float dd = fabsf(rs_l[i] - rs_l[j]);
        a = adjI[gi] * (1.f - rW[gi]*dd) * m_l[i] * m_l[j];
      }
      adjh[i*68+jl] = a;
    }
    __syncthreads();
    for (int jb=0; jb<16; jb++){
      float4 av[4];
#pragma unroll
      for (int ii=0;ii<4;ii++) av[ii] = *(const float4*)&adjh[(i0+ii)*68 + jb*4];
#pragma unroll
      for (int jj=0;jj<4;jj++){
        int jl = jb*4 + jj;
        float4 xlo = *(const float4*)&xt[jl*68 + f0];
        float4 xhi = *(const float4*)&xt[jl*68 + f0 + 4];
        float xr = xt[jl*68 + 64];
#pragma unroll
        for (int ii=0;ii<4;ii++){
          float a = (jj==0)?av[ii].x:(jj==1)?av[ii].y:(jj==2)?av[ii].z:av[ii].w;
          aL[ii].x = fmaf(a, xlo.x, aL[ii].x); aL[ii].y = fmaf(a, xlo.y, aL[ii].y);
          aL[ii].z = fmaf(a, xlo.z, aL[ii].z); aL[ii].w = fmaf(a, xlo.w, aL[ii].w);
          aH[ii].x = fmaf(a, xhi.x, aH[ii].x); aH[ii].y = fmaf(a, xhi.y, aH[ii].y);
          aH[ii].z = fmaf(a, xhi.z, aH[ii].z); aH[ii].w = fmaf(a, xhi.w, aH[ii].w);
          a64[ii] = fmaf(a, xr, a64[ii]);      // redundant x8, only ft==0 stores
        }
      }
    }
  }
#pragma unroll
  for (int ii=0;ii<4;ii++){
    int i = i0 + ii;
    size_t base = WS_CX + (size_t)i*33280 + (size_t)rc*65 + f0;
    ws[base+0]=aL[ii].x; ws[base+1]=aL[ii].y; ws[base+2]=aL[ii].z; ws[base+3]=aL[ii].w;
    ws[base+4]=aH[ii].x; ws[base+5]=aH[ii].y; ws[base+6]=aH[ii].z; ws[base+7]=aH[ii].w;
    if (ft == 0) ws[WS_CX + (size_t)i*33280 + (size_t)rc*65 + 64] = a64[ii];
  }
}

// ---------------- P4b (per chunk): per-node GEMMs for x-part of gates ----------------
// g=0: gateXr = combX@WxR+bR ; g=1: gateXu ; g=2: candX = xtilde@WxC+bC
__global__ __launch_bounds__(256) void p4b(const float* __restrict__ obs,
      const int* __restrict__ lengths, float* __restrict__ ws, int c0){
  int bid = blockIdx.x;                 // 1536 = 3 * 128 * 4
  int g = bid >> 9; int r2 = bid & 511; int n = r2 >> 2; int tile = r2 & 3;
  __shared__ float A[128*69];
  __shared__ float Wl[65*64];
  __shared__ float bl[64];
  __shared__ int slen[32];
  int tid = threadIdx.x;
  if (tid < 32) slen[tid] = lengths[tid];
  for (int idx=tid; idx<4160; idx+=256) Wl[idx] = ws[WS_WX + (size_t)(g*128+n)*4160 + idx];
  if (tid < 64) bl[tid] = ws[WS_BF + (g*128+n)*64 + tid];
  if (g < 2){
    const float* src = &ws[WS_CX + (size_t)n*33280 + (size_t)tile*8320];
    for (int idx=tid; idx<8320; idx+=256){
      int r = idx/65, f = idx - r*65;
      A[r*69+f] = src[idx];
    }
  } else {
    for (int idx=tid; idx<8320; idx+=256){
      int r = idx/65, f = idx - r*65;
      int grow = tile*128 + r;              // b*16+tl
      int gb = grow>>4, t = c0 + (grow&15);
      float v = (f < 64) ? obs[(size_t)(gb*64+t)*8192 + n*64 + f]
                         : ws[WS_RS + (gb*64+t)*128 + n];
      A[r*69+f] = v;
    }
  }
  __syncthreads();
  int rt8 = tid>>4, dq = tid&15;
  float4 acc[8];
#pragma unroll
  for (int rr=0;rr<8;rr++) acc[rr] = make_float4(0,0,0,0);
  for (int k=0;k<65;k++){
    float4 w = *(const float4*)&Wl[k*64 + dq*4];
#pragma unroll
    for (int rr=0;rr<8;rr++){
      float a = A[(rt8*8+rr)*69 + k];
      acc[rr].x = fmaf(a,w.x,acc[rr].x); acc[rr].y = fmaf(a,w.y,acc[rr].y);
      acc[rr].z = fmaf(a,w.z,acc[rr].z); acc[rr].w = fmaf(a,w.w,acc[rr].w);
    }
  }
  float4 b4 = *(const float4*)&bl[dq*4];
  float* dst = &ws[(g==0)?WS_GXR:(g==1)?WS_GXU:WS_CXC];
#pragma unroll
  for (int rr=0;rr<8;rr++){
    int grow = tile*128 + rt8*8 + rr;       // b*16+tl
    int gb = grow>>4, gtl = grow&15;
    if (c0 + gtl < slen[gb]){
      float4 o; o.x=acc[rr].x+b4.x; o.y=acc[rr].y+b4.y; o.z=acc[rr].z+b4.z; o.w=acc[rr].w+b4.w;
      *(float4*)&dst[((size_t)(n*16+gtl)*32 + gb)*64 + dq*4] = o;
    }
  }
}

// ---------------- Recurrent persistent kernel (per chunk of 16 steps) ----------------
// 256 WGs, two roles per step. A-role: (bA=bid>>3, slice sl=bid&7) computes combH rows.
// B-role: (nB=bid>>1, batch-half hf=bid&1) computes gates + h update, h-weights in LDS.
// Monotone flags on absolute t: cflag[b] +8/step (A done); hflag[b][g] +16/step (B done).
__global__ __launch_bounds__(256) void krec(const float* __restrict__ mask,
      const int* __restrict__ lengths, const float* __restrict__ adjI,
      const float* __restrict__ rWm, float* __restrict__ out, float* __restrict__ ws,
      int c0){
  unsigned* flags = (unsigned*)ws;   // [0..31]=cflag, [32..287]=hflag[b][g]
  int bid = blockIdx.x, tid = threadIdx.x;
  int bA = bid>>3, sl = bid&7; int i0 = sl*16;
  int nB = bid>>1, hf = bid&1; int b0 = hf*16;
  __shared__ float swh[3*4096];      // whr | whu | whc for node nB
  __shared__ float sbuf[2176];       // A: adjrow[16][129] ; B: chl[16][68] + h1l[16][68]
  __shared__ float rs_l[128], m_l[128];
  __shared__ int   slen[16];
  __shared__ float smB[16];
  for (int idx=tid; idx<12288; idx+=256){
    int g = idx>>12;
    swh[idx] = ws[WS_WH + (size_t)(g*128+nB)*4096 + (idx&4095)];
  }
  if (tid < 16) slen[tid] = lengths[b0+tid];
  int lenA = lengths[bA];
  __syncthreads();
  float* hbuf  = &ws[WS_H];
  float* chbuf = &ws[WS_CH];

  for (int t=c0; t<c0+16; t++){
    // ---------- A phase ----------
    if (t > 0){
      if (tid < 8){
        unsigned target = 16u*(unsigned)t;
        int guard = 0;
        while (__hip_atomic_load(&flags[32 + bA*8 + tid], __ATOMIC_RELAXED,
                 __HIP_MEMORY_SCOPE_AGENT) < target && ++guard < (1<<22))
          __builtin_amdgcn_s_sleep(1);
        __threadfence();   // acquire
      }
      __syncthreads();
    }
    bool aliveA = (t < lenA);
    if (aliveA){
      if (tid < 128) rs_l[tid] = ws[WS_RS + (bA*64+t)*128 + tid];
      else           m_l[tid-128] = mask[(bA*64+t)*128 + (tid-128)];
      __syncthreads();
      for (int idx=tid; idx<2048; idx+=256){
        int ii = idx>>7, j = idx&127, i = i0+ii;
        float a;
        if (i == j) a = 1.f;
        else {
          int gi = i*128 + j;
          float dd = fabsf(rs_l[i] - rs_l[j]);
          a = adjI[gi]*(1.f - rWm[gi]*dd)*m_l[i]*m_l[j];
        }
        sbuf[ii*129 + j] = a;
      }
      __syncthreads();
      int ii = tid>>4, dq = tid&15;
      float4 acc = make_float4(0,0,0,0);
      const float* hb = &hbuf[(size_t)bA*8192 + dq*4];
#pragma unroll 4
      for (int j=0;j<128;j++){
        float a = sbuf[ii*129 + j];
        float4 h4 = *(const float4*)&hb[j*64];
        acc.x = fmaf(a,h4.x,acc.x); acc.y = fmaf(a,h4.y,acc.y);
        acc.z = fmaf(a,h4.z,acc.z); acc.w = fmaf(a,h4.w,acc.w);
      }
      *(float4*)&chbuf[((size_t)bA*128 + i0+ii)*64 + dq*4] = acc;
    }
    __syncthreads();   // drain combH stores
    if (tid == 0)
      __hip_atomic_fetch_add(&flags[bA], 1u, __ATOMIC_RELEASE, __HIP_MEMORY_SCOPE_AGENT);

    // ---------- B phase ----------
    if (tid < 16){
      unsigned target = 8u*(unsigned)(t+1);
      int guard = 0;
      while (__hip_atomic_load(&flags[b0+tid], __ATOMIC_RELAXED,
               __HIP_MEMORY_SCOPE_AGENT) < target && ++guard < (1<<22))
        __builtin_amdgcn_s_sleep(1);
      __threadfence();
    }
    __syncthreads();
    int bi = tid>>4, dq = tid&15;
    int bb = b0 + bi;
    bool alive = (t < slen[bi]);
    float* chl = sbuf;            // [16][68]
    float* h1l = sbuf + 1088;     // [16][68]
    if (alive){
      float4 c4 = *(const float4*)&chbuf[((size_t)bb*128 + nB)*64 + dq*4];
      *(float4*)&chl[bi*68 + dq*4] = c4;
      if (dq == 0) smB[bi] = mask[(bb*64+t)*128 + nB];
    }
    __syncthreads();
    float4 h1, u4, h2; bool obs_ = false;
    int tl = t - c0;
    if (alive){
      size_t gof = ((size_t)(nB*16+tl)*32 + bb)*64 + dq*4;
      float4 ar = *(const float4*)&ws[WS_GXR + gof];
      float4 au = *(const float4*)&ws[WS_GXU + gof];
      float4 ho = *(const float4*)&hbuf[((size_t)bb*128 + nB)*64 + dq*4];
#pragma unroll 8
      for (int k=0;k<64;k++){
        float c = chl[bi*68 + k];
        float4 wr  = *(const float4*)&swh[k*64 + dq*4];
        float4 wu4 = *(const float4*)&swh[4096 + k*64 + dq*4];
        ar.x = fmaf(c,wr.x,ar.x);  ar.y = fmaf(c,wr.y,ar.y);
        ar.z = fmaf(c,wr.z,ar.z);  ar.w = fmaf(c,wr.w,ar.w);
        au.x = fmaf(c,wu4.x,au.x); au.y = fmaf(c,wu4.y,au.y);
        au.z = fmaf(c,wu4.z,au.z); au.w = fmaf(c,wu4.w,au.w);
      }
      float4 r4; r4.x=sigm(ar.x); r4.y=sigm(ar.y); r4.z=sigm(ar.z); r4.w=sigm(ar.w);
      u4.x=sigm(au.x); u4.y=sigm(au.y); u4.z=sigm(au.z); u4.w=sigm(au.w);
      obs_ = (smB[bi] > 0.f);
      h1.x = obs_ ? r4.x*ho.x : ho.x; h1.y = obs_ ? r4.y*ho.y : ho.y;
      h1.z = obs_ ? r4.z*ho.z : ho.z; h1.w = obs_ ? r4.w*ho.w : ho.w;
      *(float4*)&h1l[bi*68 + dq*4] = h1;
    }
    __syncthreads();
    if (alive){
      size_t gof = ((size_t)(nB*16+tl)*32 + bb)*64 + dq*4;
      float4 ac = *(const float4*)&ws[WS_CXC + gof];
#pragma unroll 8
      for (int k=0;k<64;k++){
        float c1 = h1l[bi*68 + k];
        float4 wc = *(const float4*)&swh[8192 + k*64 + dq*4];
        ac.x = fmaf(c1,wc.x,ac.x); ac.y = fmaf(c1,wc.y,ac.y);
        ac.z = fmaf(c1,wc.z,ac.z); ac.w = fmaf(c1,wc.w,ac.w);
      }
      float4 cd; cd.x=tanhf(ac.x); cd.y=tanhf(ac.y); cd.z=tanhf(ac.z); cd.w=tanhf(ac.w);
      h2.x = obs_ ? (1.f-u4.x)*h1.x + u4.x*cd.x : h1.x;
      h2.y = obs_ ? (1.f-u4.y)*h1.y + u4.y*cd.y : h1.y;
      h2.z = obs_ ? (1.f-u4.z)*h1.z + u4.z*cd.z : h1.z;
      h2.w = obs_ ? (1.f-u4.w)*h1.w + u4.w*cd.w : h1.w;
      *(float4*)&hbuf[((size_t)bb*128 + nB)*64 + dq*4] = h2;
      if (t == slen[bi]-1)
        *(float4*)&out[((size_t)bb*128 + nB)*64 + dq*4] = h2;
    }
    __syncthreads();   // drain h stores
    if (tid < 16)
      __hip_atomic_fetch_add(&flags[32 + (b0+tid)*8 + (nB>>4)], 1u,
                             __ATOMIC_RELEASE, __HIP_MEMORY_SCOPE_AGENT);
  }
}

extern "C" void kernel_launch(void* const* d_in, const int* in_sizes, int n_in,
                              void* d_out, int out_size, void* d_ws, size_t ws_size,
                              hipStream_t stream){
  const float* obs  = (const float*)d_in[0];
  const float* maskp= (const float*)d_in[2];
  const int*   lens = (const int*)d_in[5];
  const float* avg  = (const float*)d_in[6];
  const float* vpe  = (const float*)d_in[7];
  const float* rW   = (const float*)d_in[8];
  const float* adjI = (const float*)d_in[9];
  const float* W1   = (const float*)d_in[10];
  const float* b1   = (const float*)d_in[11];
  const float* W2   = (const float*)d_in[12];
  const float* b2   = (const float*)d_in[13];
  const float* Wu   = (const float*)d_in[14];
  const float* bu   = (const float*)d_in[15];
  const float* Wr   = (const float*)d_in[16];
  const float* br   = (const float*)d_in[17];
  const float* Wc   = (const float*)d_in[18];
  const float* bc   = (const float*)d_in[19];
  float* out = (float*)d_out;
  float* ws  = (float*)d_ws;
  // flags + h state must be zeroed every launch (ws is poisoned 0xAA)
  hipMemsetAsync(d_ws, 0, 4096, stream);
  hipMemsetAsync((char*)d_ws + WS_H*sizeof(float), 0, 262144*sizeof(float), stream);
  k_vv  <<<128, 256, 0, stream>>>(vpe, W1, b1, W2, b2, ws);
  k_fold<<<384, 256, 0, stream>>>(Wr, Wu, Wc, br, bu, bc, ws);
  k_tot <<<16,  256, 0, stream>>>(maskp, ws);
  k_rs  <<<1024,256, 0, stream>>>(avg, ws);
  for (int c = 0; c < 4; c++){
    int c0 = c*16;
    p4a <<<512, 256, 0, stream>>>(obs, maskp, adjI, rW, lens, ws, c0);
    p4b <<<1536,256, 0, stream>>>(obs, lens, ws, c0);
    krec<<<256, 256, 0, stream>>>(maskp, lens, adjI, rW, out, ws, c0);
  }
}

// Round 3
// 3215.447 us; speedup vs baseline: 1.0764x; 1.0764x over previous
//
#include <hip/hip_runtime.h>
#include <math.h>

// Problem constants: B=32, T=64, N=128, D=64, E=5.  Time chunked: TC=16, 4 chunks.
// Workspace layout (float element offsets; flags occupy first 4 KB as uint32)
constexpr size_t WS_VV  = 1024;
constexpr size_t WS_TOT = 2048;
constexpr size_t WS_RS  = 8192;                  // 262144
constexpr size_t WS_WH  = 270336;                // 3*128*64*64 = 1572864 (Wr|Wu|Wc h-part)
constexpr size_t WS_WX  = 1843200;               // 3*128*65*64 = 1597440
constexpr size_t WS_BF  = 3440640;               // 3*128*64
constexpr size_t WS_H   = 3465216;               // 262144 (recurrent state; MALL-coherent)
constexpr size_t WS_CH  = 3727360;               // 262144 (combH; MALL-coherent)
constexpr size_t WS_CX  = 3989504;               // 128*512*65 = 4259840   [n][b*16+tl][65]
constexpr size_t WS_GXR = 8249344;               // 128*16*32*64 = 4194304 [n][tl][b][o]
constexpr size_t WS_GXU = 12443648;
constexpr size_t WS_CXC = 16637952;
// end = 20832256 floats = 79.5 MiB

__device__ __forceinline__ float sigm(float x){ return 1.f/(1.f+expf(-x)); }

// MALL-coherent (agent-scope, relaxed => sc0 sc1, NO cache invalidates) 8B ld/st
__device__ __forceinline__ float2 ld2_mall(const float* p){
  union { unsigned long long u; float2 f; } cv;
  cv.u = __hip_atomic_load((const unsigned long long*)p, __ATOMIC_RELAXED,
                           __HIP_MEMORY_SCOPE_AGENT);
  return cv.f;
}
__device__ __forceinline__ void st2_mall(float* p, float a, float b){
  union { unsigned long long u; float2 f; } cv;
  cv.f = make_float2(a, b);
  __hip_atomic_store((unsigned long long*)p, cv.u, __ATOMIC_RELAXED,
                     __HIP_MEMORY_SCOPE_AGENT);
}

// ---------------- vv = relu(vpe@W1+b1)@W2+b2 ----------------
__global__ void k_vv(const float* __restrict__ vpe, const float* __restrict__ W1,
                     const float* __restrict__ b1, const float* __restrict__ W2,
                     const float* __restrict__ b2, float* __restrict__ ws){
  int n = blockIdx.x, tid = threadIdx.x;
  __shared__ float hid[128];
  if (tid < 128){
    float acc = b1[tid];
    for (int k=0;k<768;k++) acc = fmaf(vpe[n*768+k], W1[k*128+tid], acc);
    hid[tid] = fmaxf(acc, 0.f);
  }
  __syncthreads();
  if (tid < 5){
    float acc = b2[tid];
    for (int h=0;h<128;h++) acc = fmaf(hid[h], W2[h*5+tid], acc);
    ws[WS_VV + n*5 + tid] = acc;
  }
}

// ---------------- fold per-node weights: Wn = sum_e vv[n,e]*W[e] ----------------
__global__ void k_fold(const float* __restrict__ Wr, const float* __restrict__ Wu,
                       const float* __restrict__ Wc, const float* __restrict__ br,
                       const float* __restrict__ bu, const float* __restrict__ bc,
                       float* __restrict__ ws){
  int bid = blockIdx.x; int g = bid>>7; int n = bid&127;
  const float* W  = (g==0)?Wr:(g==1)?Wu:Wc;
  const float* bb = (g==0)?br:(g==1)?bu:bc;
  float v[5];
#pragma unroll
  for (int e=0;e<5;e++) v[e] = ws[WS_VV + n*5 + e];
  for (int idx=threadIdx.x; idx<129*64; idx+=256){
    int i = idx>>6, o = idx&63;
    float a = 0.f;
#pragma unroll
    for (int e=0;e<5;e++) a = fmaf(v[e], W[(e*129+i)*64+o], a);
    if (i < 65) ws[WS_WX + (size_t)(g*128+n)*4160 + i*64 + o] = a;
    else        ws[WS_WH + (size_t)(g*128+n)*4096 + (i-65)*64 + o] = a;
  }
  if (threadIdx.x < 64){
    int o = threadIdx.x; float a = 0.f;
#pragma unroll
    for (int e=0;e<5;e++) a = fmaf(v[e], bb[e*64+o], a);
    ws[WS_BF + (g*128+n)*64 + o] = a;
  }
}

// ---------------- tot[b,n] = sum_t mask ----------------
__global__ void k_tot(const float* __restrict__ mask, float* __restrict__ ws){
  int id = blockIdx.x*256 + threadIdx.x;     // 4096
  int b = id>>7, n = id&127;
  float s = 0.f;
  for (int t=0;t<64;t++) s += mask[(b*64+t)*128 + n];
  ws[WS_TOT + b*128 + n] = s;
}

// ---------------- rs = 0.5*tanh(avg/(tot+1)) ----------------
__global__ void k_rs(const float* __restrict__ avg, float* __restrict__ ws){
  int id = blockIdx.x*256 + threadIdx.x;     // 262144
  int b = id>>13, n = id&127;
  float tot = ws[WS_TOT + b*128 + n];
  ws[WS_RS + id] = 0.5f * tanhf(avg[id] / (tot + 1.f));
}

// ---------------- P4a (per chunk): combX = adj @ xtilde, stored [i][b*16+tl][65] ----------------
__global__ __launch_bounds__(256) void p4a(const float* __restrict__ obs,
      const float* __restrict__ mask, const float* __restrict__ adjI,
      const float* __restrict__ rW, const int* __restrict__ lengths,
      float* __restrict__ ws, int c0){
  int rc = blockIdx.x;                 // b*16 + tl
  int b = rc>>4, tl = rc&15, t = c0 + tl;
  if (t >= lengths[b]) return;
  int rt = b*64 + t;
  __shared__ float xt[64*68];
  __shared__ float adjh[128*68];
  __shared__ float rs_l[128], m_l[128];
  int tid = threadIdx.x;
  if (tid < 128){ rs_l[tid] = ws[WS_RS + rt*128 + tid]; m_l[tid] = mask[rt*128 + tid]; }
  __syncthreads();
  int it = tid>>3, ft = tid&7, i0 = it*4, f0 = ft*8;
  float4 aL[4], aH[4]; float a64[4];
#pragma unroll
  for (int ii=0;ii<4;ii++){ aL[ii]=make_float4(0,0,0,0); aH[ii]=make_float4(0,0,0,0); a64[ii]=0.f; }
  for (int half=0; half<2; half++){
    __syncthreads();
    int j0 = half*64;
    for (int idx=tid; idx<4096; idx+=256){
      int jl = idx>>6, f = idx&63;
      xt[jl*68+f] = obs[(size_t)rt*8192 + (j0+jl)*64 + f];
    }
    if (tid < 64) xt[tid*68+64] = rs_l[j0+tid];
    for (int idx=tid; idx<8192; idx+=256){
      int i = idx>>6, jl = idx&63, j = j0+jl;
      float a;
      if (i == j) a = 1.f;
      else {
        int gi = i*128 + j;
        float dd = fabsf(rs_l[i] - rs_l[j]);
        a = adjI[gi] * (1.f - rW[gi]*dd) * m_l[i] * m_l[j];
      }
      adjh[i*68+jl] = a;
    }
    __syncthreads();
    for (int jb=0; jb<16; jb++){
      float4 av[4];
#pragma unroll
      for (int ii=0;ii<4;ii++) av[ii] = *(const float4*)&adjh[(i0+ii)*68 + jb*4];
#pragma unroll
      for (int jj=0;jj<4;jj++){
        int jl = jb*4 + jj;
        float4 xlo = *(const float4*)&xt[jl*68 + f0];
        float4 xhi = *(const float4*)&xt[jl*68 + f0 + 4];
        float xr = xt[jl*68 + 64];
#pragma unroll
        for (int ii=0;ii<4;ii++){
          float a = (jj==0)?av[ii].x:(jj==1)?av[ii].y:(jj==2)?av[ii].z:av[ii].w;
          aL[ii].x = fmaf(a, xlo.x, aL[ii].x); aL[ii].y = fmaf(a, xlo.y, aL[ii].y);
          aL[ii].z = fmaf(a, xlo.z, aL[ii].z); aL[ii].w = fmaf(a, xlo.w, aL[ii].w);
          aH[ii].x = fmaf(a, xhi.x, aH[ii].x); aH[ii].y = fmaf(a, xhi.y, aH[ii].y);
          aH[ii].z = fmaf(a, xhi.z, aH[ii].z); aH[ii].w = fmaf(a, xhi.w, aH[ii].w);
          a64[ii] = fmaf(a, xr, a64[ii]);
        }
      }
    }
  }
#pragma unroll
  for (int ii=0;ii<4;ii++){
    int i = i0 + ii;
    size_t base = WS_CX + (size_t)i*33280 + (size_t)rc*65 + f0;
    ws[base+0]=aL[ii].x; ws[base+1]=aL[ii].y; ws[base+2]=aL[ii].z; ws[base+3]=aL[ii].w;
    ws[base+4]=aH[ii].x; ws[base+5]=aH[ii].y; ws[base+6]=aH[ii].z; ws[base+7]=aH[ii].w;
    if (ft == 0) ws[WS_CX + (size_t)i*33280 + (size_t)rc*65 + 64] = a64[ii];
  }
}

// ---------------- P4b (per chunk): per-node GEMMs for x-part of gates ----------------
__global__ __launch_bounds__(256) void p4b(const float* __restrict__ obs,
      const int* __restrict__ lengths, float* __restrict__ ws, int c0){
  int bid = blockIdx.x;                 // 1536 = 3 * 128 * 4
  int g = bid >> 9; int r2 = bid & 511; int n = r2 >> 2; int tile = r2 & 3;
  __shared__ float A[128*69];
  __shared__ float Wl[65*64];
  __shared__ float bl[64];
  __shared__ int slen[32];
  int tid = threadIdx.x;
  if (tid < 32) slen[tid] = lengths[tid];
  for (int idx=tid; idx<4160; idx+=256) Wl[idx] = ws[WS_WX + (size_t)(g*128+n)*4160 + idx];
  if (tid < 64) bl[tid] = ws[WS_BF + (g*128+n)*64 + tid];
  if (g < 2){
    const float* src = &ws[WS_CX + (size_t)n*33280 + (size_t)tile*8320];
    for (int idx=tid; idx<8320; idx+=256){
      int r = idx/65, f = idx - r*65;
      A[r*69+f] = src[idx];
    }
  } else {
    for (int idx=tid; idx<8320; idx+=256){
      int r = idx/65, f = idx - r*65;
      int grow = tile*128 + r;              // b*16+tl
      int gb = grow>>4, t = c0 + (grow&15);
      float v = (f < 64) ? obs[(size_t)(gb*64+t)*8192 + n*64 + f]
                         : ws[WS_RS + (gb*64+t)*128 + n];
      A[r*69+f] = v;
    }
  }
  __syncthreads();
  int rt8 = tid>>4, dq = tid&15;
  float4 acc[8];
#pragma unroll
  for (int rr=0;rr<8;rr++) acc[rr] = make_float4(0,0,0,0);
  for (int k=0;k<65;k++){
    float4 w = *(const float4*)&Wl[k*64 + dq*4];
#pragma unroll
    for (int rr=0;rr<8;rr++){
      float a = A[(rt8*8+rr)*69 + k];
      acc[rr].x = fmaf(a,w.x,acc[rr].x); acc[rr].y = fmaf(a,w.y,acc[rr].y);
      acc[rr].z = fmaf(a,w.z,acc[rr].z); acc[rr].w = fmaf(a,w.w,acc[rr].w);
    }
  }
  float4 b4 = *(const float4*)&bl[dq*4];
  float* dst = &ws[(g==0)?WS_GXR:(g==1)?WS_GXU:WS_CXC];
#pragma unroll
  for (int rr=0;rr<8;rr++){
    int grow = tile*128 + rt8*8 + rr;
    int gb = grow>>4, gtl = grow&15;
    if (c0 + gtl < slen[gb]){
      float4 o; o.x=acc[rr].x+b4.x; o.y=acc[rr].y+b4.y; o.z=acc[rr].z+b4.z; o.w=acc[rr].w+b4.w;
      *(float4*)&dst[((size_t)(n*16+gtl)*32 + gb)*64 + dq*4] = o;
    }
  }
}

// ---------------- Recurrent persistent kernel (per chunk of 16 steps) ----------------
// 256 blocks x 64 threads (1 wave). A-role: (bA=bid>>3, 16-row slice) computes combH.
// B-role: (nB=bid>>1, batch-half) computes gates + h update; Wr/Wu in LDS, Wc from L2,
// h state in registers. Cross-block data via MALL (sc0sc1) atomics; relaxed flags +
// explicit vmcnt(0) release. NO acquire/release fences => NO L2 invalidates.
__global__ __launch_bounds__(64) void krec(const float* __restrict__ mask,
      const int* __restrict__ lengths, const float* __restrict__ adjI,
      const float* __restrict__ rWm, float* __restrict__ out, float* __restrict__ ws,
      int c0){
  unsigned* flags = (unsigned*)ws;   // [0..31]=cflag, [32..287]=hflag[b][g]
  const int bid = blockIdx.x, tid = threadIdx.x;
  const int bA = bid>>3, sl = bid&7, i0 = sl*16;
  const int nB = bid>>1, hf = bid&1, b0 = hf*16;
  __shared__ float swh[8192];        // Wr | Wu for node nB (32 KB)
  __shared__ float adjT[2560];       // [j][il] stride 20 (A-role)
  __shared__ float cT[1280];         // [k][bi] stride 20 (chl, then h1)
  __shared__ float rs_l[128], m_l[128];
  float* hbuf  = &ws[WS_H];
  float* chbuf = &ws[WS_CH];
  const float* wcg = &ws[WS_WH + (size_t)(256+nB)*4096];   // Wc streamed from L2

  for (int idx=tid; idx<2048; idx+=64){
    float4 v = *(const float4*)&ws[WS_WH + (size_t)((idx>>10)*128+nB)*4096 + (size_t)(idx&1023)*4];
    *(float4*)&swh[idx*4] = v;
  }
  const int lenA = lengths[bA];
  const int bq = tid>>4, dq = tid&15;
  int bbv[4], slenv[4];
  float4 hst[4];
#pragma unroll
  for (int c=0;c<4;c++){
    int bb = b0 + bq*4 + c;
    bbv[c] = bb; slenv[c] = lengths[bb];
    const float* hp = &hbuf[((size_t)bb*128+nB)*64 + dq*4];
    float2 lo = ld2_mall(hp), hi = ld2_mall(hp+2);
    hst[c] = make_float4(lo.x, lo.y, hi.x, hi.y);
  }
  __syncthreads();

  for (int t=c0; t<c0+16; t++){
    // ---------- A phase ----------
    if (t > 0){
      if (tid < 8){
        unsigned target = 16u*(unsigned)t; int guard = 0;
        while (__hip_atomic_load(&flags[32 + bA*8 + tid], __ATOMIC_RELAXED,
                 __HIP_MEMORY_SCOPE_AGENT) < target && ++guard < (1<<22))
          __builtin_amdgcn_s_sleep(1);
      }
      __syncthreads();
    }
    if (t < lenA){
      for (int idx=tid; idx<128; idx+=64){
        rs_l[idx] = ws[WS_RS + (size_t)(bA*64+t)*128 + idx];
        m_l[idx]  = mask[(size_t)(bA*64+t)*128 + idx];
      }
      __syncthreads();
      for (int idx=tid; idx<2048; idx+=64){
        int j = idx&127, il = idx>>7, I = i0+il;
        float a;
        if (I == j) a = 1.f;
        else {
          int gi = I*128 + j;
          float dd = fabsf(rs_l[I] - rs_l[j]);
          a = adjI[gi]*(1.f - rWm[gi]*dd)*m_l[I]*m_l[j];
        }
        adjT[j*20 + il] = a;
      }
      __syncthreads();
      float4 acc[4];
#pragma unroll
      for (int c=0;c<4;c++) acc[c] = make_float4(0,0,0,0);
      const float* hbA = &hbuf[(size_t)bA*8192 + dq*4];
#pragma unroll 4
      for (int j=0;j<128;j++){
        float4 a4 = *(const float4*)&adjT[j*20 + bq*4];
        float2 lo = ld2_mall(&hbA[j*64]);
        float2 hi = ld2_mall(&hbA[j*64 + 2]);
        acc[0].x = fmaf(a4.x,lo.x,acc[0].x); acc[0].y = fmaf(a4.x,lo.y,acc[0].y);
        acc[0].z = fmaf(a4.x,hi.x,acc[0].z); acc[0].w = fmaf(a4.x,hi.y,acc[0].w);
        acc[1].x = fmaf(a4.y,lo.x,acc[1].x); acc[1].y = fmaf(a4.y,lo.y,acc[1].y);
        acc[1].z = fmaf(a4.y,hi.x,acc[1].z); acc[1].w = fmaf(a4.y,hi.y,acc[1].w);
        acc[2].x = fmaf(a4.z,lo.x,acc[2].x); acc[2].y = fmaf(a4.z,lo.y,acc[2].y);
        acc[2].z = fmaf(a4.z,hi.x,acc[2].z); acc[2].w = fmaf(a4.z,hi.y,acc[2].w);
        acc[3].x = fmaf(a4.w,lo.x,acc[3].x); acc[3].y = fmaf(a4.w,lo.y,acc[3].y);
        acc[3].z = fmaf(a4.w,hi.x,acc[3].z); acc[3].w = fmaf(a4.w,hi.y,acc[3].w);
      }
#pragma unroll
      for (int c=0;c<4;c++){
        float* cp = &chbuf[((size_t)bA*128 + i0 + bq*4 + c)*64 + dq*4];
        st2_mall(cp,   acc[c].x, acc[c].y);
        st2_mall(cp+2, acc[c].z, acc[c].w);
      }
    }
    asm volatile("s_waitcnt vmcnt(0)" ::: "memory");   // release: drain combH stores
    if (tid == 0)
      __hip_atomic_fetch_add(&flags[bA], 1u, __ATOMIC_RELAXED, __HIP_MEMORY_SCOPE_AGENT);

    // ---------- B phase ----------
    const int tl = t - c0;
    float4 ar[4], au[4], ac[4]; float ms[4];
#pragma unroll
    for (int c=0;c<4;c++){   // prefetch gate-X tensors (independent of flags)
      size_t gof = ((size_t)(nB*16+tl)*32 + bbv[c])*64 + dq*4;
      ar[c] = *(const float4*)&ws[WS_GXR + gof];
      au[c] = *(const float4*)&ws[WS_GXU + gof];
      ac[c] = *(const float4*)&ws[WS_CXC + gof];
      ms[c] = mask[(size_t)(bbv[c]*64+t)*128 + nB];
    }
    if (tid < 16){
      unsigned target = 8u*(unsigned)(t+1); int guard = 0;
      while (__hip_atomic_load(&flags[b0+tid], __ATOMIC_RELAXED,
               __HIP_MEMORY_SCOPE_AGENT) < target && ++guard < (1<<22))
        __builtin_amdgcn_s_sleep(1);
    }
    __syncthreads();
    for (int idx=tid; idx<512; idx+=64){   // stage chl transposed [k][bi]
      int bi = idx>>5, fp = idx&31;
      float2 v = ld2_mall(&chbuf[((size_t)(b0+bi)*128 + nB)*64 + fp*2]);
      cT[(fp*2)*20 + bi]   = v.x;
      cT[(fp*2+1)*20 + bi] = v.y;
    }
    __syncthreads();
#pragma unroll 4
    for (int k=0;k<64;k++){
      float4 wr = *(const float4*)&swh[k*64 + dq*4];
      float4 wu = *(const float4*)&swh[4096 + k*64 + dq*4];
      float4 cc = *(const float4*)&cT[k*20 + bq*4];
      const float* cp = (const float*)&cc;
#pragma unroll
      for (int c=0;c<4;c++){
        float cv = cp[c];
        ar[c].x = fmaf(cv,wr.x,ar[c].x); ar[c].y = fmaf(cv,wr.y,ar[c].y);
        ar[c].z = fmaf(cv,wr.z,ar[c].z); ar[c].w = fmaf(cv,wr.w,ar[c].w);
        au[c].x = fmaf(cv,wu.x,au[c].x); au[c].y = fmaf(cv,wu.y,au[c].y);
        au[c].z = fmaf(cv,wu.z,au[c].z); au[c].w = fmaf(cv,wu.w,au[c].w);
      }
    }
    float4 h1[4], uu[4];
#pragma unroll
    for (int c=0;c<4;c++){
      float4 r;
      r.x = sigm(ar[c].x); r.y = sigm(ar[c].y); r.z = sigm(ar[c].z); r.w = sigm(ar[c].w);
      uu[c].x = sigm(au[c].x); uu[c].y = sigm(au[c].y);
      uu[c].z = sigm(au[c].z); uu[c].w = sigm(au[c].w);
      bool ob = ms[c] > 0.f;
      h1[c].x = ob ? r.x*hst[c].x : hst[c].x;
      h1[c].y = ob ? r.y*hst[c].y : hst[c].y;
      h1[c].z = ob ? r.z*hst[c].z : hst[c].z;
      h1[c].w = ob ? r.w*hst[c].w : hst[c].w;
    }
    __syncthreads();   // all lanes done reading chl from cT
#pragma unroll
    for (int c=0;c<4;c++){
      const float* hp = (const float*)&h1[c];
#pragma unroll
      for (int q=0;q<4;q++) cT[(dq*4+q)*20 + bq*4 + c] = hp[q];
    }
    __syncthreads();
#pragma unroll 4
    for (int k=0;k<64;k++){
      float4 wc = *(const float4*)&wcg[k*64 + dq*4];    // L2-hot stream
      float4 hh = *(const float4*)&cT[k*20 + bq*4];
      const float* hp = (const float*)&hh;
#pragma unroll
      for (int c=0;c<4;c++){
        float hv = hp[c];
        ac[c].x = fmaf(hv,wc.x,ac[c].x); ac[c].y = fmaf(hv,wc.y,ac[c].y);
        ac[c].z = fmaf(hv,wc.z,ac[c].z); ac[c].w = fmaf(hv,wc.w,ac[c].w);
      }
    }
#pragma unroll
    for (int c=0;c<4;c++){
      if (t < slenv[c]){
        float4 cd;
        cd.x = tanhf(ac[c].x); cd.y = tanhf(ac[c].y);
        cd.z = tanhf(ac[c].z); cd.w = tanhf(ac[c].w);
        bool ob = ms[c] > 0.f;
        float4 h2;
        h2.x = ob ? (1.f-uu[c].x)*h1[c].x + uu[c].x*cd.x : h1[c].x;
        h2.y = ob ? (1.f-uu[c].y)*h1[c].y + uu[c].y*cd.y : h1[c].y;
        h2.z = ob ? (1.f-uu[c].z)*h1[c].z + uu[c].z*cd.z : h1[c].z;
        h2.w = ob ? (1.f-uu[c].w)*h1[c].w + uu[c].w*cd.w : h1[c].w;
        hst[c] = h2;
        float* hp2 = &hbuf[((size_t)bbv[c]*128 + nB)*64 + dq*4];
        st2_mall(hp2,   h2.x, h2.y);
        st2_mall(hp2+2, h2.z, h2.w);
        if (t == slenv[c]-1)
          *(float4*)&out[((size_t)bbv[c]*128 + nB)*64 + dq*4] = h2;
      }
    }
    asm volatile("s_waitcnt vmcnt(0)" ::: "memory");   // release: drain h stores
    if (tid < 16)
      __hip_atomic_fetch_add(&flags[32 + (b0+tid)*8 + (nB>>4)], 1u,
                             __ATOMIC_RELAXED, __HIP_MEMORY_SCOPE_AGENT);
  }
}

extern "C" void kernel_launch(void* const* d_in, const int* in_sizes, int n_in,
                              void* d_out, int out_size, void* d_ws, size_t ws_size,
                              hipStream_t stream){
  const float* obs  = (const float*)d_in[0];
  const float* maskp= (const float*)d_in[2];
  const int*   lens = (const int*)d_in[5];
  const float* avg  = (const float*)d_in[6];
  const float* vpe  = (const float*)d_in[7];
  const float* rW   = (const float*)d_in[8];
  const float* adjI = (const float*)d_in[9];
  const float* W1   = (const float*)d_in[10];
  const float* b1   = (const float*)d_in[11];
  const float* W2   = (const float*)d_in[12];
  const float* b2   = (const float*)d_in[13];
  const float* Wu   = (const float*)d_in[14];
  const float* bu   = (const float*)d_in[15];
  const float* Wr   = (const float*)d_in[16];
  const float* br   = (const float*)d_in[17];
  const float* Wc   = (const float*)d_in[18];
  const float* bc   = (const float*)d_in[19];
  float* out = (float*)d_out;
  float* ws  = (float*)d_ws;
  hipMemsetAsync(d_ws, 0, 4096, stream);
  hipMemsetAsync((char*)d_ws + WS_H*sizeof(float), 0, 262144*sizeof(float), stream);
  k_vv  <<<128, 256, 0, stream>>>(vpe, W1, b1, W2, b2, ws);
  k_fold<<<384, 256, 0, stream>>>(Wr, Wu, Wc, br, bu, bc, ws);
  k_tot <<<16,  256, 0, stream>>>(maskp, ws);
  k_rs  <<<1024,256, 0, stream>>>(avg, ws);
  for (int c = 0; c < 4; c++){
    int c0 = c*16;
    p4a <<<512, 256, 0, stream>>>(obs, maskp, adjI, rW, lens, ws, c0);
    p4b <<<1536,256, 0, stream>>>(obs, lens, ws, c0);
    krec<<<256, 64, 0, stream>>>(maskp, lens, adjI, rW, out, ws, c0);
  }
}

// Round 4
// 1527.775 us; speedup vs baseline: 2.2655x; 2.1047x over previous
//
#include <hip/hip_runtime.h>
#include <math.h>

// Problem constants: B=32, T=64, N=128, D=64, E=5.  Time chunked: TC=16, 4 chunks.
// Workspace layout (float element offsets; flags occupy first 4 KB as uint32)
constexpr size_t WS_VV  = 1024;
constexpr size_t WS_TOT = 2048;
constexpr size_t WS_RS  = 8192;                  // 262144
constexpr size_t WS_WH  = 270336;                // 3*128*64*64 = 1572864 (Wr|Wu|Wc h-part)
constexpr size_t WS_WX  = 1843200;               // 3*128*65*64 = 1597440
constexpr size_t WS_BF  = 3440640;               // 3*128*64
constexpr size_t WS_H   = 3465216;               // 262144 (recurrent state; MALL-coherent)
constexpr size_t WS_CH  = 3727360;               // (unused this round)
constexpr size_t WS_CX  = 3989504;               // 128*512*65 = 4259840   [n][b*16+tl][65]
constexpr size_t WS_GXR = 8249344;               // 128*16*32*64 = 4194304 [n][tl][b][o]
constexpr size_t WS_GXU = 12443648;
constexpr size_t WS_CXC = 16637952;
// end = 20832256 floats = 79.5 MiB

__device__ __forceinline__ float sigm(float x){ return 1.f/(1.f+expf(-x)); }

// MALL-coherent (agent-scope relaxed => sc0 sc1, no cache maintenance) 8B ld/st
__device__ __forceinline__ float2 ld2_mall(const float* p){
  union { unsigned long long u; float2 f; } cv;
  cv.u = __hip_atomic_load((const unsigned long long*)p, __ATOMIC_RELAXED,
                           __HIP_MEMORY_SCOPE_AGENT);
  return cv.f;
}
__device__ __forceinline__ void st2_mall(float* p, float a, float b){
  union { unsigned long long u; float2 f; } cv;
  cv.f = make_float2(a, b);
  __hip_atomic_store((unsigned long long*)p, cv.u, __ATOMIC_RELAXED,
                     __HIP_MEMORY_SCOPE_AGENT);
}

// ---------------- vv = relu(vpe@W1+b1)@W2+b2 ----------------
__global__ void k_vv(const float* __restrict__ vpe, const float* __restrict__ W1,
                     const float* __restrict__ b1, const float* __restrict__ W2,
                     const float* __restrict__ b2, float* __restrict__ ws){
  int n = blockIdx.x, tid = threadIdx.x;
  __shared__ float hid[128];
  if (tid < 128){
    float acc = b1[tid];
    for (int k=0;k<768;k++) acc = fmaf(vpe[n*768+k], W1[k*128+tid], acc);
    hid[tid] = fmaxf(acc, 0.f);
  }
  __syncthreads();
  if (tid < 5){
    float acc = b2[tid];
    for (int h=0;h<128;h++) acc = fmaf(hid[h], W2[h*5+tid], acc);
    ws[WS_VV + n*5 + tid] = acc;
  }
}

// ---------------- fold per-node weights: Wn = sum_e vv[n,e]*W[e] ----------------
__global__ void k_fold(const float* __restrict__ Wr, const float* __restrict__ Wu,
                       const float* __restrict__ Wc, const float* __restrict__ br,
                       const float* __restrict__ bu, const float* __restrict__ bc,
                       float* __restrict__ ws){
  int bid = blockIdx.x; int g = bid>>7; int n = bid&127;
  const float* W  = (g==0)?Wr:(g==1)?Wu:Wc;
  const float* bb = (g==0)?br:(g==1)?bu:bc;
  float v[5];
#pragma unroll
  for (int e=0;e<5;e++) v[e] = ws[WS_VV + n*5 + e];
  for (int idx=threadIdx.x; idx<129*64; idx+=256){
    int i = idx>>6, o = idx&63;
    float a = 0.f;
#pragma unroll
    for (int e=0;e<5;e++) a = fmaf(v[e], W[(e*129+i)*64+o], a);
    if (i < 65) ws[WS_WX + (size_t)(g*128+n)*4160 + i*64 + o] = a;
    else        ws[WS_WH + (size_t)(g*128+n)*4096 + (i-65)*64 + o] = a;
  }
  if (threadIdx.x < 64){
    int o = threadIdx.x; float a = 0.f;
#pragma unroll
    for (int e=0;e<5;e++) a = fmaf(v[e], bb[e*64+o], a);
    ws[WS_BF + (g*128+n)*64 + o] = a;
  }
}

// ---------------- tot[b,n] = sum_t mask ----------------
__global__ void k_tot(const float* __restrict__ mask, float* __restrict__ ws){
  int id = blockIdx.x*256 + threadIdx.x;     // 4096
  int b = id>>7, n = id&127;
  float s = 0.f;
  for (int t=0;t<64;t++) s += mask[(b*64+t)*128 + n];
  ws[WS_TOT + b*128 + n] = s;
}

// ---------------- rs = 0.5*tanh(avg/(tot+1)) ----------------
__global__ void k_rs(const float* __restrict__ avg, float* __restrict__ ws){
  int id = blockIdx.x*256 + threadIdx.x;     // 262144
  int b = id>>13, n = id&127;
  float tot = ws[WS_TOT + b*128 + n];
  ws[WS_RS + id] = 0.5f * tanhf(avg[id] / (tot + 1.f));
}

// ---------------- P4a (per chunk): combX = adj @ xtilde, stored [i][b*16+tl][65] ----------------
__global__ __launch_bounds__(256) void p4a(const float* __restrict__ obs,
      const float* __restrict__ mask, const float* __restrict__ adjI,
      const float* __restrict__ rW, const int* __restrict__ lengths,
      float* __restrict__ ws, int c0){
  int rc = blockIdx.x;                 // b*16 + tl
  int b = rc>>4, tl = rc&15, t = c0 + tl;
  if (t >= lengths[b]) return;
  int rt = b*64 + t;
  __shared__ float xt[64*68];
  __shared__ float adjh[128*68];
  __shared__ float rs_l[128], m_l[128];
  int tid = threadIdx.x;
  if (tid < 128){ rs_l[tid] = ws[WS_RS + rt*128 + tid]; m_l[tid] = mask[rt*128 + tid]; }
  __syncthreads();
  int it = tid>>3, ft = tid&7, i0 = it*4, f0 = ft*8;
  float4 aL[4], aH[4]; float a64[4];
#pragma unroll
  for (int ii=0;ii<4;ii++){ aL[ii]=make_float4(0,0,0,0); aH[ii]=make_float4(0,0,0,0); a64[ii]=0.f; }
  for (int half=0; half<2; half++){
    __syncthreads();
    int j0 = half*64;
    for (int idx=tid; idx<4096; idx+=256){
      int jl = idx>>6, f = idx&63;
      xt[jl*68+f] = obs[(size_t)rt*8192 + (j0+jl)*64 + f];
    }
    if (tid < 64) xt[tid*68+64] = rs_l[j0+tid];
    for (int idx=tid; idx<8192; idx+=256){
      int i = idx>>6, jl = idx&63, j = j0+jl;
      float a;
      if (i == j) a = 1.f;
      else {
        int gi = i*128 + j;
        float dd = fabsf(rs_l[i] - rs_l[j]);
        a = adjI[gi] * (1.f - rW[gi]*dd) * m_l[i] * m_l[j];
      }
      adjh[i*68+jl] = a;
    }
    __syncthreads();
    for (int jb=0; jb<16; jb++){
      float4 av[4];
#pragma unroll
      for (int ii=0;ii<4;ii++) av[ii] = *(const float4*)&adjh[(i0+ii)*68 + jb*4];
#pragma unroll
      for (int jj=0;jj<4;jj++){
        int jl = jb*4 + jj;
        float4 xlo = *(const float4*)&xt[jl*68 + f0];
        float4 xhi = *(const float4*)&xt[jl*68 + f0 + 4];
        float xr = xt[jl*68 + 64];
#pragma unroll
        for (int ii=0;ii<4;ii++){
          float a = (jj==0)?av[ii].x:(jj==1)?av[ii].y:(jj==2)?av[ii].z:av[ii].w;
          aL[ii].x = fmaf(a, xlo.x, aL[ii].x); aL[ii].y = fmaf(a, xlo.y, aL[ii].y);
          aL[ii].z = fmaf(a, xlo.z, aL[ii].z); aL[ii].w = fmaf(a, xlo.w, aL[ii].w);
          aH[ii].x = fmaf(a, xhi.x, aH[ii].x); aH[ii].y = fmaf(a, xhi.y, aH[ii].y);
          aH[ii].z = fmaf(a, xhi.z, aH[ii].z); aH[ii].w = fmaf(a, xhi.w, aH[ii].w);
          a64[ii] = fmaf(a, xr, a64[ii]);
        }
      }
    }
  }
#pragma unroll
  for (int ii=0;ii<4;ii++){
    int i = i0 + ii;
    size_t base = WS_CX + (size_t)i*33280 + (size_t)rc*65 + f0;
    ws[base+0]=aL[ii].x; ws[base+1]=aL[ii].y; ws[base+2]=aL[ii].z; ws[base+3]=aL[ii].w;
    ws[base+4]=aH[ii].x; ws[base+5]=aH[ii].y; ws[base+6]=aH[ii].z; ws[base+7]=aH[ii].w;
    if (ft == 0) ws[WS_CX + (size_t)i*33280 + (size_t)rc*65 + 64] = a64[ii];
  }
}

// ---------------- P4b (per chunk): per-node GEMMs for x-part of gates (incl. bias) ----------------
__global__ __launch_bounds__(256) void p4b(const float* __restrict__ obs,
      const int* __restrict__ lengths, float* __restrict__ ws, int c0){
  int bid = blockIdx.x;                 // 1536 = 3 * 128 * 4
  int g = bid >> 9; int r2 = bid & 511; int n = r2 >> 2; int tile = r2 & 3;
  __shared__ float A[128*69];
  __shared__ float Wl[65*64];
  __shared__ float bl[64];
  __shared__ int slen[32];
  int tid = threadIdx.x;
  if (tid < 32) slen[tid] = lengths[tid];
  for (int idx=tid; idx<4160; idx+=256) Wl[idx] = ws[WS_WX + (size_t)(g*128+n)*4160 + idx];
  if (tid < 64) bl[tid] = ws[WS_BF + (g*128+n)*64 + tid];
  if (g < 2){
    const float* src = &ws[WS_CX + (size_t)n*33280 + (size_t)tile*8320];
    for (int idx=tid; idx<8320; idx+=256){
      int r = idx/65, f = idx - r*65;
      A[r*69+f] = src[idx];
    }
  } else {
    for (int idx=tid; idx<8320; idx+=256){
      int r = idx/65, f = idx - r*65;
      int grow = tile*128 + r;              // b*16+tl
      int gb = grow>>4, t = c0 + (grow&15);
      float v = (f < 64) ? obs[(size_t)(gb*64+t)*8192 + n*64 + f]
                         : ws[WS_RS + (gb*64+t)*128 + n];
      A[r*69+f] = v;
    }
  }
  __syncthreads();
  int rt8 = tid>>4, dq = tid&15;
  float4 acc[8];
#pragma unroll
  for (int rr=0;rr<8;rr++) acc[rr] = make_float4(0,0,0,0);
  for (int k=0;k<65;k++){
    float4 w = *(const float4*)&Wl[k*64 + dq*4];
#pragma unroll
    for (int rr=0;rr<8;rr++){
      float a = A[(rt8*8+rr)*69 + k];
      acc[rr].x = fmaf(a,w.x,acc[rr].x); acc[rr].y = fmaf(a,w.y,acc[rr].y);
      acc[rr].z = fmaf(a,w.z,acc[rr].z); acc[rr].w = fmaf(a,w.w,acc[rr].w);
    }
  }
  float4 b4 = *(const float4*)&bl[dq*4];
  float* dst = &ws[(g==0)?WS_GXR:(g==1)?WS_GXU:WS_CXC];
#pragma unroll
  for (int rr=0;rr<8;rr++){
    int grow = tile*128 + rt8*8 + rr;
    int gb = grow>>4, gtl = grow&15;
    if (c0 + gtl < slen[gb]){
      float4 o; o.x=acc[rr].x+b4.x; o.y=acc[rr].y+b4.y; o.z=acc[rr].z+b4.z; o.w=acc[rr].w+b4.w;
      *(float4*)&dst[((size_t)(n*16+gtl)*32 + gb)*64 + dq*4] = o;
    }
  }
}

// ---------------- Recurrent persistent kernel v4 (fused roles, per chunk) ----------------
// 256 blocks x 256 threads. Block (bA=bid>>3, s=bid&7) owns nodes s*16..s*16+16 of batch bA:
// computes its combH rows AND its nodes' gates+h-update. ONE batch-local sync/step:
// 8 sibling blocks exchange h via MALL; flags are plain per-producer dword stores
// (zero atomics; consumers poll 8 consecutive dwords = 1 line). Weights streamed from
// L2 (bid=b*8+s keeps node-slice s on one XCD under round-robin dispatch; perf-only).
__global__ __launch_bounds__(256) void krec(const float* __restrict__ mask,
      const int* __restrict__ lengths, const float* __restrict__ adjI,
      const float* __restrict__ rWm, float* __restrict__ out, float* __restrict__ ws,
      int c0){
  unsigned* hfl = (unsigned*)ws;           // hfl[bA*8+s] = completed steps (monotone)
  const int bid = blockIdx.x, tid = threadIdx.x;
  const int bA = bid>>3, s = bid&7, ns = s*16;
  __shared__ float hs[8192];       // staged h[bA]  [node][f]           32 KB
  __shared__ float adjT[2560];     // adj [j][il] stride 20             10.24 KB
  __shared__ float chT[1088];      // combH exchange [n_local][k] s68    4.35 KB
  __shared__ float hT[1088];       // h1 exchange    [n_local][k] s68    4.35 KB
  __shared__ float rs_l[128], m_l[128];
  const int lenA = lengths[bA];
  const int ng = tid>>6, fA = tid&63;      // A-GEMM mapping: 4 rows x 1 feature
  const int nl = tid>>4, fq = tid&15;      // gate mapping: 1 node x 4 features
  const int n  = ns + nl;
  float* hbuf = &ws[WS_H];
  const float* wrg = &ws[WS_WH + (size_t)(0*128+n)*4096];
  const float* wug = &ws[WS_WH + (size_t)(1*128+n)*4096];
  const float* wcg = &ws[WS_WH + (size_t)(2*128+n)*4096];

  for (int t=c0; t<c0+16; t++){
    if (t >= lenA){       // dead batch: keep flag count moving (block-uniform branch)
      if (tid == 0)
        __hip_atomic_store(&hfl[bid], (unsigned)(t+1), __ATOMIC_RELAXED,
                           __HIP_MEMORY_SCOPE_AGENT);
      __syncthreads();
      continue;
    }
    // ---- step-known prework (overlaps siblings' previous-step production) ----
    if (tid < 128) rs_l[tid] = ws[WS_RS + (size_t)(bA*64+t)*128 + tid];
    else           m_l[tid-128] = mask[(size_t)(bA*64+t)*128 + (tid-128)];
    __syncthreads();
    for (int idx=tid; idx<2048; idx+=256){
      int j = idx&127, il = idx>>7, I = ns+il;
      float a;
      if (I == j) a = 1.f;
      else {
        int gi = I*128 + j;
        float dd = fabsf(rs_l[I] - rs_l[j]);
        a = adjI[gi]*(1.f - rWm[gi]*dd)*m_l[I]*m_l[j];
      }
      adjT[j*20 + il] = a;
    }
    const int tl = t - c0;
    size_t gof = ((size_t)(n*16+tl)*32 + bA)*64 + fq*4;
    float4 arv = *(const float4*)&ws[WS_GXR + gof];   // x-parts (incl. bias)
    float4 auv = *(const float4*)&ws[WS_GXU + gof];
    float4 acv = *(const float4*)&ws[WS_CXC + gof];
    float  msv = m_l[n];
    // ---- wait for siblings' h(t-1) ----
    if (t > 0){
      if (tid < 8){
        unsigned tgt = (unsigned)t; int guard = 0;
        while (__hip_atomic_load(&hfl[bA*8 + tid], __ATOMIC_RELAXED,
                 __HIP_MEMORY_SCOPE_AGENT) < tgt && ++guard < (1<<20))
          __builtin_amdgcn_s_sleep(2);
      }
    }
    __syncthreads();     // adjT built + poll done
    // ---- stage full h[bA] into LDS (coalesced MALL 8B loads) ----
#pragma unroll
    for (int k=0;k<16;k++){
      int p = tid + 256*k;
      float2 v = ld2_mall(&hbuf[(size_t)bA*8192 + 2*p]);
      *(float2*)&hs[2*p] = v;
    }
    __syncthreads();
    // ---- combH rows: acc[r] = sum_j adj[I,j] * h[j, fA] ----
    float acc[4] = {0.f,0.f,0.f,0.f};
#pragma unroll 4
    for (int j=0;j<128;j++){
      float hv = hs[j*64 + fA];
      float4 a4 = *(const float4*)&adjT[j*20 + ng*4];
      acc[0] = fmaf(a4.x, hv, acc[0]);
      acc[1] = fmaf(a4.y, hv, acc[1]);
      acc[2] = fmaf(a4.z, hv, acc[2]);
      acc[3] = fmaf(a4.w, hv, acc[3]);
    }
#pragma unroll
    for (int r=0;r<4;r++) chT[(ng*4+r)*68 + fA] = acc[r];
    __syncthreads();
    // ---- r/u gates: += combH[n,:] @ Wh (L2-streamed weights) ----
#pragma unroll 4
    for (int k=0;k<64;k++){
      float cv = chT[nl*68 + k];
      float4 wr4 = *(const float4*)&wrg[k*64 + fq*4];
      float4 wu4 = *(const float4*)&wug[k*64 + fq*4];
      arv.x = fmaf(cv,wr4.x,arv.x); arv.y = fmaf(cv,wr4.y,arv.y);
      arv.z = fmaf(cv,wr4.z,arv.z); arv.w = fmaf(cv,wr4.w,arv.w);
      auv.x = fmaf(cv,wu4.x,auv.x); auv.y = fmaf(cv,wu4.y,auv.y);
      auv.z = fmaf(cv,wu4.z,auv.z); auv.w = fmaf(cv,wu4.w,auv.w);
    }
    float4 rr4, uu4, h1;
    rr4.x = sigm(arv.x); rr4.y = sigm(arv.y); rr4.z = sigm(arv.z); rr4.w = sigm(arv.w);
    uu4.x = sigm(auv.x); uu4.y = sigm(auv.y); uu4.z = sigm(auv.z); uu4.w = sigm(auv.w);
    float4 hown = *(const float4*)&hs[n*64 + fq*4];
    bool ob = msv > 0.f;
    h1.x = ob ? rr4.x*hown.x : hown.x;
    h1.y = ob ? rr4.y*hown.y : hown.y;
    h1.z = ob ? rr4.z*hown.z : hown.z;
    h1.w = ob ? rr4.w*hown.w : hown.w;
    *(float4*)&hT[nl*68 + fq*4] = h1;
    __syncthreads();
    // ---- candidate: += h1[n,:] @ Wc ----
#pragma unroll 4
    for (int k=0;k<64;k++){
      float hv1 = hT[nl*68 + k];
      float4 wc4 = *(const float4*)&wcg[k*64 + fq*4];
      acv.x = fmaf(hv1,wc4.x,acv.x); acv.y = fmaf(hv1,wc4.y,acv.y);
      acv.z = fmaf(hv1,wc4.z,acv.z); acv.w = fmaf(hv1,wc4.w,acv.w);
    }
    float4 cd, h2;
    cd.x = tanhf(acv.x); cd.y = tanhf(acv.y); cd.z = tanhf(acv.z); cd.w = tanhf(acv.w);
    h2.x = ob ? (1.f-uu4.x)*h1.x + uu4.x*cd.x : h1.x;
    h2.y = ob ? (1.f-uu4.y)*h1.y + uu4.y*cd.y : h1.y;
    h2.z = ob ? (1.f-uu4.z)*h1.z + uu4.z*cd.z : h1.z;
    h2.w = ob ? (1.f-uu4.w)*h1.w + uu4.w*cd.w : h1.w;
    float* hp = &hbuf[((size_t)bA*128 + n)*64 + fq*4];
    st2_mall(hp,   h2.x, h2.y);
    st2_mall(hp+2, h2.z, h2.w);
    if (t == lenA-1)
      *(float4*)&out[((size_t)bA*128 + n)*64 + fq*4] = h2;
    __syncthreads();   // everyone done with hs/chT/hT/rs_l/m_l before next iter
    asm volatile("s_waitcnt vmcnt(0)" ::: "memory");   // release: h stores visible
    if (tid == 0)
      __hip_atomic_store(&hfl[bid], (unsigned)(t+1), __ATOMIC_RELAXED,
                         __HIP_MEMORY_SCOPE_AGENT);
  }
}

extern "C" void kernel_launch(void* const* d_in, const int* in_sizes, int n_in,
                              void* d_out, int out_size, void* d_ws, size_t ws_size,
                              hipStream_t stream){
  const float* obs  = (const float*)d_in[0];
  const float* maskp= (const float*)d_in[2];
  const int*   lens = (const int*)d_in[5];
  const float* avg  = (const float*)d_in[6];
  const float* vpe  = (const float*)d_in[7];
  const float* rW   = (const float*)d_in[8];
  const float* adjI = (const float*)d_in[9];
  const float* W1   = (const float*)d_in[10];
  const float* b1   = (const float*)d_in[11];
  const float* W2   = (const float*)d_in[12];
  const float* b2   = (const float*)d_in[13];
  const float* Wu   = (const float*)d_in[14];
  const float* bu   = (const float*)d_in[15];
  const float* Wr   = (const float*)d_in[16];
  const float* br   = (const float*)d_in[17];
  const float* Wc   = (const float*)d_in[18];
  const float* bc   = (const float*)d_in[19];
  float* out = (float*)d_out;
  float* ws  = (float*)d_ws;
  hipMemsetAsync(d_ws, 0, 4096, stream);
  hipMemsetAsync((char*)d_ws + WS_H*sizeof(float), 0, 262144*sizeof(float), stream);
  k_vv  <<<128, 256, 0, stream>>>(vpe, W1, b1, W2, b2, ws);
  k_fold<<<384, 256, 0, stream>>>(Wr, Wu, Wc, br, bu, bc, ws);
  k_tot <<<16,  256, 0, stream>>>(maskp, ws);
  k_rs  <<<1024,256, 0, stream>>>(avg, ws);
  for (int c = 0; c < 4; c++){
    int c0 = c*16;
    p4a <<<512, 256, 0, stream>>>(obs, maskp, adjI, rW, lens, ws, c0);
    p4b <<<1536,256, 0, stream>>>(obs, lens, ws, c0);
    krec<<<256, 256, 0, stream>>>(maskp, lens, adjI, rW, out, ws, c0);
  }
}